// Round 2
// baseline (21769.958 us; speedup 1.0000x reference)
//
#include <hip/hip_runtime.h>

// Problem constants
#define BB 32      // batch
#define SS 512     // seq len
#define II 512     // input size
#define HH 512     // hidden
#define GG 2048    // 4*H

typedef unsigned short u16;
typedef unsigned int   u32;

typedef __attribute__((ext_vector_type(8))) short bf16x8;
typedef __attribute__((ext_vector_type(4))) float f32x4;

__device__ __forceinline__ float b2f(u16 h) {
    return __uint_as_float(((u32)h) << 16);
}
__device__ __forceinline__ u16 f2b(float f) {  // RNE f32 -> bf16
    u32 u = __float_as_uint(f);
    u32 r = (u + 0x7FFFu + ((u >> 16) & 1u)) >> 16;
    return (u16)r;
}

// ---- global_load_lds helper (16B per lane, uniform LDS base + lane*16) ----
#ifndef __has_builtin
#define __has_builtin(x) 0
#endif
#if __has_builtin(__builtin_amdgcn_global_load_lds)
#define HAVE_GLL 1
#else
#define HAVE_GLL 0
#endif

typedef __attribute__((address_space(1))) void as1_void;
typedef __attribute__((address_space(3))) void as3_void;

__device__ __forceinline__ void gload16(const void* g, void* l, int lane) {
#if HAVE_GLL
    __builtin_amdgcn_global_load_lds((as1_void*)g, (as3_void*)l, 16, 0, 0);
#else
    *(bf16x8*)((char*)l + lane * 16) = *(const bf16x8*)g;
#endif
}

// ---------------- convert x: [B][S][I] f32 -> [S][B][I] bf16 ----------------
__global__ void k_convert_x(const float* __restrict__ x, u16* __restrict__ xbf) {
    const int n4 = BB * SS * II / 4;  // 2,097,152
    for (int e4 = blockIdx.x * blockDim.x + threadIdx.x; e4 < n4;
         e4 += gridDim.x * blockDim.x) {
        int e = e4 * 4;
        int s = e >> 14;         // / (B*I = 16384)
        int b = (e >> 9) & 31;
        int i = e & 511;
        float4 v = *(const float4*)(x + (size_t)b * (SS * II) + (size_t)s * II + i);
        ushort4 o;
        o.x = f2b(v.x); o.y = f2b(v.y); o.z = f2b(v.z); o.w = f2b(v.w);
        *(ushort4*)(xbf + (size_t)s * (BB * II) + (size_t)b * II + i) = o;
    }
}

// ---------------- generic f32 -> bf16 cast ----------------
__global__ void k_cast(const float* __restrict__ src, u16* __restrict__ dst, int n4) {
    for (int e4 = blockIdx.x * blockDim.x + threadIdx.x; e4 < n4;
         e4 += gridDim.x * blockDim.x) {
        float4 v = *(const float4*)(src + (size_t)e4 * 4);
        ushort4 o;
        o.x = f2b(v.x); o.y = f2b(v.y); o.z = f2b(v.z); o.w = f2b(v.w);
        *(ushort4*)(dst + (size_t)e4 * 4) = o;
    }
}

// ---------------- input projection GEMM (128x128 tile, BK=64, MFMA bf16) ----
// xp[m][n] = sum_k A[m][k]*W[n][k] + b_ih[n] + b_hh[n]
// A: [16384][K] bf16, W: [2048][K] bf16, out bf16 [16384][2048].
// LDS tiles [128][64] bf16 with 16B-chunk XOR swizzle: phys_chunk = log_chunk ^ (row&7).
#define BKP 64

__launch_bounds__(256)
__global__ void k_proj(const u16* __restrict__ A,
                       const u16* __restrict__ Wf_, const u16* __restrict__ Wb_,
                       const float* __restrict__ bihf, const float* __restrict__ bhhf,
                       const float* __restrict__ bihb, const float* __restrict__ bhhb,
                       u16* __restrict__ xpf, u16* __restrict__ xpb,
                       int K) {
    const int dir = blockIdx.z;
    const u16* Wm = dir ? Wb_ : Wf_;
    const float* bih = dir ? bihb : bihf;
    const float* bhh = dir ? bhhb : bhhf;
    u16* xp = dir ? xpb : xpf;

    __shared__ __align__(16) u16 As[128 * BKP];
    __shared__ __align__(16) u16 Bs[128 * BKP];

    const int t    = threadIdx.x;
    const int lane = t & 63;
    const int w    = t >> 6;
    const int wm   = w >> 1, wn = w & 1;
    const int m0   = blockIdx.x * 128;
    const int n0   = blockIdx.y * 128;

    f32x4 acc[4][4] = {};

    for (int kt = 0; kt < K; kt += BKP) {
        // stage A and B: 1024 chunks of 16B each, per wave 4 instr per matrix
        #pragma unroll
        for (int i = 0; i < 4; ++i) {
            int c   = (w * 4 + i) * 64 + lane;   // physical chunk 0..1023
            int row = c >> 3;
            int lc  = (c & 7) ^ (row & 7);       // logical chunk within row
            int gk  = kt + lc * 8;
            gload16(A  + (size_t)(m0 + row) * K + gk, (char*)As + (w * 4 + i) * 1024, lane);
            gload16(Wm + (size_t)(n0 + row) * K + gk, (char*)Bs + (w * 4 + i) * 1024, lane);
        }
        __syncthreads();   // drains vmcnt (global_load_lds) + makes LDS visible

        #pragma unroll
        for (int ks = 0; ks < 2; ++ks) {
            const int kc = ks * 4 + (lane >> 4);   // logical 8-elem chunk idx
            bf16x8 af[4], bfr[4];
            #pragma unroll
            for (int mi = 0; mi < 4; ++mi) {
                int row = wm * 64 + mi * 16 + (lane & 15);
                af[mi] = *(const bf16x8*)&As[row * BKP + ((kc ^ (row & 7)) << 3)];
            }
            #pragma unroll
            for (int ni = 0; ni < 4; ++ni) {
                int row = wn * 64 + ni * 16 + (lane & 15);
                bfr[ni] = *(const bf16x8*)&Bs[row * BKP + ((kc ^ (row & 7)) << 3)];
            }
            #pragma unroll
            for (int mi = 0; mi < 4; ++mi)
                #pragma unroll
                for (int ni = 0; ni < 4; ++ni)
                    acc[mi][ni] = __builtin_amdgcn_mfma_f32_16x16x32_bf16(
                        af[mi], bfr[ni], acc[mi][ni], 0, 0, 0);
        }
        __syncthreads();
    }

    // epilogue: C/D layout col = lane&15, row = (lane>>4)*4 + r
    #pragma unroll
    for (int ni = 0; ni < 4; ++ni) {
        int n = n0 + wn * 64 + ni * 16 + (lane & 15);
        float bias = bih[n] + bhh[n];
        #pragma unroll
        for (int mi = 0; mi < 4; ++mi) {
            #pragma unroll
            for (int r = 0; r < 4; ++r) {
                int m = m0 + wm * 64 + mi * 16 + (lane >> 4) * 4 + r;
                xp[(size_t)m * GG + n] = f2b(acc[mi][ni][r] + bias);
            }
        }
    }
}

// ---------------- persistent recurrence kernel ----------------
// grid = 64 WGs x 256 thr. dir = bid>>5, wg = bid&31 owns 16 h-cols j0..j0+15
// (64 gate rows). W_hh slice packed in LDS in MFMA fragment order (once).
// Per step: gates = xp + h_prev @ Whh^T via mfma 16x16x32 (4 waves k-split),
// elementwise in f32, c in LDS, h exchanged via global ping-pong + flag barrier.
__launch_bounds__(256)
__global__ void k_rec(const u16* __restrict__ xpf, const u16* __restrict__ xpb,
                      const float* __restrict__ whf, const float* __restrict__ whb,
                      u16* __restrict__ hbuf,        // [2 parity][2 dir][32][512] bf16
                      u32* __restrict__ flags,       // [2 dir][32 wg] stride 16 u32
                      u16* __restrict__ hs0,         // layer0 out [s][b][1024] bf16
                      float* __restrict__ out,       // layer1 out [b][s][1024] f32
                      float* __restrict__ fin,       // final h (65536 f32) then c
                      int layer) {
    const int bid  = blockIdx.x;
    const int dir  = bid >> 5;
    const int wg   = bid & 31;
    const int j0   = wg * 16;
    const u16*  xp = dir ? xpb : xpf;
    const float* W = dir ? whb : whf;
    u32* myflags   = flags + dir * 512;

    const int t    = threadIdx.x;
    const int lane = t & 63;
    const int kq   = t >> 6;           // wave id = k-quarter

    __shared__ __align__(16) u16 Wfr[64 * 64 * 8];   // 64 blocks(g,kt) x 64 lanes x 8 bf16
    __shared__ float gates[32 * 65];
    __shared__ float xq[32 * 65];
    __shared__ float cl[32 * 17];

    // ---- pack W_hh slice into fragment order (once) ----
    for (int it = 0; it < 16; ++it) {
        int task = it * 256 + t;           // 0..4095
        int l    = task & 63;
        int blk  = task >> 6;              // 0..63
        int g    = blk >> 4;               // gate
        int kt   = blk & 15;               // k-tile (32 elems)
        const float* src = W + (size_t)(g * 512 + j0 + (l & 15)) * 512
                             + kt * 32 + (l >> 4) * 8;
        float4 v0 = *(const float4*)src;
        float4 v1 = *(const float4*)(src + 4);
        union { bf16x8 v; u16 a[8]; } u;
        u.a[0] = f2b(v0.x); u.a[1] = f2b(v0.y); u.a[2] = f2b(v0.z); u.a[3] = f2b(v0.w);
        u.a[4] = f2b(v1.x); u.a[5] = f2b(v1.y); u.a[6] = f2b(v1.z); u.a[7] = f2b(v1.w);
        *(bf16x8*)&Wfr[task * 8] = u.v;
    }
    for (int i = t; i < 32 * 17; i += 256) cl[i] = 0.f;
    __syncthreads();

    for (int s = 0; s < SS; ++s) {
        const int sa = dir ? (SS - 1 - s) : s;
        const u16* hprev = hbuf + ((size_t)((s & 1) * 2 + dir)) * (32 * 512);
        u16*       hnext = hbuf + ((size_t)(((s & 1) ^ 1) * 2 + dir)) * (32 * 512);

        // ---- wait until all WGs of this dir finished step s-1 ----
        if (s > 0) {
            if (t < 64) {
                const u32 tgt = (u32)s;
                for (;;) {
                    u32 v = tgt;
                    if (lane < 32)
                        v = __hip_atomic_load(myflags + lane * 16, __ATOMIC_RELAXED,
                                              __HIP_MEMORY_SCOPE_AGENT);
                    if (__all(v >= tgt)) break;
                    __builtin_amdgcn_s_sleep(2);
                }
                __threadfence();   // acquire: invalidate stale L1/L2 lines
            }
            __syncthreads();
        }

        // ---- A fragments from global h_prev (issue early) ----
        bf16x8 Afr[2][4];
        const int kb = kq * 4;
        #pragma unroll
        for (int k = 0; k < 4; ++k) {
            int koff = (kb + k) * 32 + (lane >> 4) * 8;
            Afr[0][k] = *(const bf16x8*)(hprev + (lane & 15) * 512 + koff);
            Afr[1][k] = *(const bf16x8*)(hprev + ((lane & 15) + 16) * 512 + koff);
        }

        // ---- zero gates accumulator + stage xp slice (overlaps A latency) ----
        for (int i = t; i < 32 * 65; i += 256) gates[i] = 0.f;
        if (t < 128) {
            int b = t & 31, g = t >> 5;
            const u16* xsrc = xp + (size_t)(sa * 32 + b) * GG + g * 512 + j0;
            bf16x8 v0 = *(const bf16x8*)xsrc;
            bf16x8 v1 = *(const bf16x8*)(xsrc + 8);
            #pragma unroll
            for (int i = 0; i < 8; ++i) {
                xq[b * 65 + g * 16 + i]     = b2f((u16)v0[i]);
                xq[b * 65 + g * 16 + 8 + i] = b2f((u16)v1[i]);
            }
        }

        // ---- MFMA: this wave covers kt = kb..kb+3 over all 4 gates ----
        f32x4 acc[2][4];
        #pragma unroll
        for (int mi = 0; mi < 2; ++mi)
            #pragma unroll
            for (int g = 0; g < 4; ++g) acc[mi][g] = (f32x4){0.f, 0.f, 0.f, 0.f};

        #pragma unroll
        for (int k = 0; k < 4; ++k) {
            #pragma unroll
            for (int g = 0; g < 4; ++g) {
                bf16x8 Bv = *(const bf16x8*)&Wfr[((size_t)((g * 16 + kb + k) * 64 + lane)) * 8];
                acc[0][g] = __builtin_amdgcn_mfma_f32_16x16x32_bf16(Afr[0][k], Bv, acc[0][g], 0, 0, 0);
                acc[1][g] = __builtin_amdgcn_mfma_f32_16x16x32_bf16(Afr[1][k], Bv, acc[1][g], 0, 0, 0);
            }
        }

        __syncthreads();   // gates zeroed + xq staged before reduction

        #pragma unroll
        for (int mi = 0; mi < 2; ++mi)
            #pragma unroll
            for (int g = 0; g < 4; ++g)
                #pragma unroll
                for (int r = 0; r < 4; ++r)
                    atomicAdd(&gates[(mi * 16 + (lane >> 4) * 4 + r) * 65
                                     + g * 16 + (lane & 15)], acc[mi][g][r]);

        __syncthreads();

        // ---- elementwise epilogue: thread -> (b, jj) x2 ----
        {
            int b = t & 31, j1 = t >> 5;
            #pragma unroll
            for (int h2 = 0; h2 < 2; ++h2) {
                int jj = j1 + h2 * 8;
                float gi = xq[b * 65 +      jj] + gates[b * 65 +      jj];
                float gf = xq[b * 65 + 16 + jj] + gates[b * 65 + 16 + jj];
                float gg = xq[b * 65 + 32 + jj] + gates[b * 65 + 32 + jj];
                float go = xq[b * 65 + 48 + jj] + gates[b * 65 + 48 + jj];
                float ig = 1.f / (1.f + __expf(-gi));
                float fg = 1.f / (1.f + __expf(-gf));
                float gt = tanhf(gg);
                float og = 1.f / (1.f + __expf(-go));
                float c  = fg * cl[b * 17 + jj] + ig * gt;
                float h  = og * tanhf(c);
                cl[b * 17 + jj] = c;
                hnext[b * 512 + j0 + jj] = f2b(h);
                if (layer == 0) {
                    hs0[(size_t)sa * (BB * 1024) + (size_t)b * 1024 + dir * 512 + j0 + jj] = f2b(h);
                } else {
                    out[(size_t)b * (SS * 1024) + (size_t)sa * 1024 + dir * 512 + j0 + jj] = h;
                }
                if (s == SS - 1) {
                    int sl = layer * 2 + dir;
                    fin[(size_t)sl * (32 * 512) + b * 512 + j0 + jj] = h;
                    fin[65536 + (size_t)sl * (32 * 512) + b * 512 + j0 + jj] = c;
                }
            }
        }

        // ---- publish h_next ----
        __threadfence();          // release: drain stores to coherence point
        __syncthreads();
        if (t == 0)
            __hip_atomic_store(myflags + wg * 16, (u32)(s + 1), __ATOMIC_RELAXED,
                               __HIP_MEMORY_SCOPE_AGENT);
    }
}

// ---------------- workspace layout (bytes) ----------------
#define OFF_XBF   ((size_t)0)                       // 16,777,216
#define OFF_HS0   ((size_t)16777216)                // 33,554,432
#define OFF_XPF   ((size_t)50331648)                // 67,108,864
#define OFF_XPB   ((size_t)117440512)               // 67,108,864
#define OFF_WIH0F ((size_t)184549376)               // 2,097,152
#define OFF_WIH0B ((size_t)186646528)               // 2,097,152
#define OFF_WIH1F ((size_t)188743680)               // 4,194,304
#define OFF_WIH1B ((size_t)192937984)               // 4,194,304
#define OFF_H     ((size_t)197132288)               // 131,072
#define OFF_FLAGS ((size_t)197263360)               // 4,096

extern "C" void kernel_launch(void* const* d_in, const int* in_sizes, int n_in,
                              void* d_out, int out_size, void* d_ws, size_t ws_size,
                              hipStream_t stream) {
    const float* x      = (const float*)d_in[0];
    const float* wih0f  = (const float*)d_in[1];
    const float* whh0f  = (const float*)d_in[2];
    const float* bih0f  = (const float*)d_in[3];
    const float* bhh0f  = (const float*)d_in[4];
    const float* wih0b  = (const float*)d_in[5];
    const float* whh0b  = (const float*)d_in[6];
    const float* bih0b  = (const float*)d_in[7];
    const float* bhh0b  = (const float*)d_in[8];
    const float* wih1f  = (const float*)d_in[9];
    const float* whh1f  = (const float*)d_in[10];
    const float* bih1f  = (const float*)d_in[11];
    const float* bhh1f  = (const float*)d_in[12];
    const float* wih1b  = (const float*)d_in[13];
    const float* whh1b  = (const float*)d_in[14];
    const float* bih1b  = (const float*)d_in[15];
    const float* bhh1b  = (const float*)d_in[16];

    float* out = (float*)d_out;
    char* ws = (char*)d_ws;

    u16* xbf    = (u16*)(ws + OFF_XBF);
    u16* hs0    = (u16*)(ws + OFF_HS0);
    u16* xpf    = (u16*)(ws + OFF_XPF);
    u16* xpb    = (u16*)(ws + OFF_XPB);
    u16* bwih0f = (u16*)(ws + OFF_WIH0F);
    u16* bwih0b = (u16*)(ws + OFF_WIH0B);
    u16* bwih1f = (u16*)(ws + OFF_WIH1F);
    u16* bwih1b = (u16*)(ws + OFF_WIH1B);
    u16* hbuf   = (u16*)(ws + OFF_H);
    u32* flags  = (u32*)(ws + OFF_FLAGS);
    float* fin  = out + 16777216;   // final h stack, then c stack at +65536

    // converts
    k_convert_x<<<1024, 256, 0, stream>>>(x, xbf);
    k_cast<<<512, 256, 0, stream>>>(wih0f, bwih0f, 2048 * 512 / 4);
    k_cast<<<512, 256, 0, stream>>>(wih0b, bwih0b, 2048 * 512 / 4);
    k_cast<<<512, 256, 0, stream>>>(wih1f, bwih1f, 2048 * 1024 / 4);
    k_cast<<<512, 256, 0, stream>>>(wih1b, bwih1b, 2048 * 1024 / 4);

    // layer 0
    hipMemsetAsync(ws + OFF_H, 0, 131072, stream);
    hipMemsetAsync(ws + OFF_FLAGS, 0, 4096, stream);
    k_proj<<<dim3(128, 16, 2), 256, 0, stream>>>(
        xbf, bwih0f, bwih0b, bih0f, bhh0f, bih0b, bhh0b, xpf, xpb, 512);
    k_rec<<<64, 256, 0, stream>>>(xpf, xpb, whh0f, whh0b, hbuf, flags,
                                  hs0, nullptr, fin, 0);

    // layer 1
    hipMemsetAsync(ws + OFF_H, 0, 131072, stream);
    hipMemsetAsync(ws + OFF_FLAGS, 0, 4096, stream);
    k_proj<<<dim3(128, 16, 2), 256, 0, stream>>>(
        hs0, bwih1f, bwih1b, bih1f, bhh1f, bih1b, bhh1b, xpf, xpb, 1024);
    k_rec<<<64, 256, 0, stream>>>(xpf, xpb, whh1f, whh1b, hbuf, flags,
                                  nullptr, out, fin, 1);
}

// Round 3
// 6074.546 us; speedup vs baseline: 3.5838x; 3.5838x over previous
//
#include <hip/hip_runtime.h>

// Problem constants
#define BB 32      // batch
#define SS 512     // seq len
#define II 512     // input size
#define HH 512     // hidden
#define GG 2048    // 4*H

typedef unsigned short u16;
typedef unsigned int   u32;
typedef unsigned long long u64;

typedef __attribute__((ext_vector_type(8))) short bf16x8;
typedef __attribute__((ext_vector_type(4))) float f32x4;

__device__ __forceinline__ float b2f(u16 h) {
    return __uint_as_float(((u32)h) << 16);
}
__device__ __forceinline__ u16 f2b(float f) {  // RNE f32 -> bf16
    u32 u = __float_as_uint(f);
    u32 r = (u + 0x7FFFu + ((u >> 16) & 1u)) >> 16;
    return (u16)r;
}

// ---- global_load_lds helper (16B per lane, uniform LDS base + lane*16) ----
#ifndef __has_builtin
#define __has_builtin(x) 0
#endif
#if __has_builtin(__builtin_amdgcn_global_load_lds)
#define HAVE_GLL 1
#else
#define HAVE_GLL 0
#endif

typedef __attribute__((address_space(1))) void as1_void;
typedef __attribute__((address_space(3))) void as3_void;

__device__ __forceinline__ void gload16(const void* g, void* l, int lane) {
#if HAVE_GLL
    __builtin_amdgcn_global_load_lds((as1_void*)g, (as3_void*)l, 16, 0, 0);
#else
    *(bf16x8*)((char*)l + lane * 16) = *(const bf16x8*)g;
#endif
}

// ---------------- convert x: [B][S][I] f32 -> [S][B][I] bf16 ----------------
__global__ void k_convert_x(const float* __restrict__ x, u16* __restrict__ xbf) {
    const int n4 = BB * SS * II / 4;  // 2,097,152
    for (int e4 = blockIdx.x * blockDim.x + threadIdx.x; e4 < n4;
         e4 += gridDim.x * blockDim.x) {
        int e = e4 * 4;
        int s = e >> 14;         // / (B*I = 16384)
        int b = (e >> 9) & 31;
        int i = e & 511;
        float4 v = *(const float4*)(x + (size_t)b * (SS * II) + (size_t)s * II + i);
        ushort4 o;
        o.x = f2b(v.x); o.y = f2b(v.y); o.z = f2b(v.z); o.w = f2b(v.w);
        *(ushort4*)(xbf + (size_t)s * (BB * II) + (size_t)b * II + i) = o;
    }
}

// ---------------- generic f32 -> bf16 cast ----------------
__global__ void k_cast(const float* __restrict__ src, u16* __restrict__ dst, int n4) {
    for (int e4 = blockIdx.x * blockDim.x + threadIdx.x; e4 < n4;
         e4 += gridDim.x * blockDim.x) {
        float4 v = *(const float4*)(src + (size_t)e4 * 4);
        ushort4 o;
        o.x = f2b(v.x); o.y = f2b(v.y); o.z = f2b(v.z); o.w = f2b(v.w);
        *(ushort4*)(dst + (size_t)e4 * 4) = o;
    }
}

// ---------------- input projection GEMM (128x128 tile, BK=64, MFMA bf16) ----
#define BKP 64

__launch_bounds__(256)
__global__ void k_proj(const u16* __restrict__ A,
                       const u16* __restrict__ Wf_, const u16* __restrict__ Wb_,
                       const float* __restrict__ bihf, const float* __restrict__ bhhf,
                       const float* __restrict__ bihb, const float* __restrict__ bhhb,
                       u16* __restrict__ xpf, u16* __restrict__ xpb,
                       int K) {
    const int dir = blockIdx.z;
    const u16* Wm = dir ? Wb_ : Wf_;
    const float* bih = dir ? bihb : bihf;
    const float* bhh = dir ? bhhb : bhhf;
    u16* xp = dir ? xpb : xpf;

    __shared__ __align__(16) u16 As[128 * BKP];
    __shared__ __align__(16) u16 Bs[128 * BKP];

    const int t    = threadIdx.x;
    const int lane = t & 63;
    const int w    = t >> 6;
    const int wm   = w >> 1, wn = w & 1;
    const int m0   = blockIdx.x * 128;
    const int n0   = blockIdx.y * 128;

    f32x4 acc[4][4] = {};

    for (int kt = 0; kt < K; kt += BKP) {
        #pragma unroll
        for (int i = 0; i < 4; ++i) {
            int c   = (w * 4 + i) * 64 + lane;   // physical chunk 0..1023
            int row = c >> 3;
            int lc  = (c & 7) ^ (row & 7);       // logical chunk within row
            int gk  = kt + lc * 8;
            gload16(A  + (size_t)(m0 + row) * K + gk, (char*)As + (w * 4 + i) * 1024, lane);
            gload16(Wm + (size_t)(n0 + row) * K + gk, (char*)Bs + (w * 4 + i) * 1024, lane);
        }
        __syncthreads();

        #pragma unroll
        for (int ks = 0; ks < 2; ++ks) {
            const int kc = ks * 4 + (lane >> 4);
            bf16x8 af[4], bfr[4];
            #pragma unroll
            for (int mi = 0; mi < 4; ++mi) {
                int row = wm * 64 + mi * 16 + (lane & 15);
                af[mi] = *(const bf16x8*)&As[row * BKP + ((kc ^ (row & 7)) << 3)];
            }
            #pragma unroll
            for (int ni = 0; ni < 4; ++ni) {
                int row = wn * 64 + ni * 16 + (lane & 15);
                bfr[ni] = *(const bf16x8*)&Bs[row * BKP + ((kc ^ (row & 7)) << 3)];
            }
            #pragma unroll
            for (int mi = 0; mi < 4; ++mi)
                #pragma unroll
                for (int ni = 0; ni < 4; ++ni)
                    acc[mi][ni] = __builtin_amdgcn_mfma_f32_16x16x32_bf16(
                        af[mi], bfr[ni], acc[mi][ni], 0, 0, 0);
        }
        __syncthreads();
    }

    #pragma unroll
    for (int ni = 0; ni < 4; ++ni) {
        int n = n0 + wn * 64 + ni * 16 + (lane & 15);
        float bias = bih[n] + bhh[n];
        #pragma unroll
        for (int mi = 0; mi < 4; ++mi) {
            #pragma unroll
            for (int r = 0; r < 4; ++r) {
                int m = m0 + wm * 64 + mi * 16 + (lane >> 4) * 4 + r;
                xp[(size_t)m * GG + n] = f2b(acc[mi][ni][r] + bias);
            }
        }
    }
}

// ---------------- persistent recurrence kernel (IC-coherent exchange) ------
// grid = 64 WGs x 256 thr. dir = bid>>5, wg = bid&31 owns 16 h-cols j0..j0+15.
// All cross-WG data (h ping-pong, flags) moves via relaxed AGENT-scope atomics
// (sc1: bypass non-coherent per-XCD L2, coherent at Infinity Cache). No fences.
__launch_bounds__(256)
__global__ void k_rec(const u16* __restrict__ xpf, const u16* __restrict__ xpb,
                      const float* __restrict__ whf, const float* __restrict__ whb,
                      u16* __restrict__ hbuf,        // [2 parity][2 dir][32][512] bf16
                      u32* __restrict__ flags,       // [2 dir][32 wg] stride 32 u32
                      u16* __restrict__ hs0,         // layer0 out [s][b][1024] bf16
                      float* __restrict__ out,       // layer1 out [b][s][1024] f32
                      float* __restrict__ fin,       // final h (65536 f32) then c
                      int layer) {
    const int bid  = blockIdx.x;
    const int dir  = bid >> 5;
    const int wg   = bid & 31;
    const int j0   = wg * 16;
    const u16*  xp = dir ? xpb : xpf;
    const float* W = dir ? whb : whf;
    u32* myflags   = flags + dir * 1024;

    const int t    = threadIdx.x;
    const int lane = t & 63;
    const int g    = t >> 6;           // wave id = gate

    __shared__ __align__(16) u16 Wfr[64 * 64 * 8];   // frag-order W slice (64 KB)
    __shared__ __align__(16) u16 hl[32 * 512];       // h tile, XOR-swizzled (32 KB)
    __shared__ float xq[32 * 65];                     // xp slice f32
    __shared__ float gates[4 * 32 * 16];              // per-gate planes

    // ---- pack W_hh slice into fragment order (once; layout verified r2) ----
    for (int it = 0; it < 16; ++it) {
        int task = it * 256 + t;           // 0..4095
        int l    = task & 63;
        int blk  = task >> 6;              // 0..63 = gate*16 + ktile
        int gg   = blk >> 4;
        int kt   = blk & 15;
        const float* src = W + (size_t)(gg * 512 + j0 + (l & 15)) * 512
                             + kt * 32 + (l >> 4) * 8;
        float4 v0 = *(const float4*)src;
        float4 v1 = *(const float4*)(src + 4);
        union { bf16x8 v; u16 a[8]; } u;
        u.a[0] = f2b(v0.x); u.a[1] = f2b(v0.y); u.a[2] = f2b(v0.z); u.a[3] = f2b(v0.w);
        u.a[4] = f2b(v1.x); u.a[5] = f2b(v1.y); u.a[6] = f2b(v1.z); u.a[7] = f2b(v1.w);
        *(bf16x8*)&Wfr[task * 8] = u.v;
    }
    __syncthreads();

    // c-state lives in registers of epilogue threads (t<128): 4 cols each
    float creg[4] = {0.f, 0.f, 0.f, 0.f};
    const int eb = t & 31;          // epilogue batch row
    const int ej = t >> 5;          // epilogue col group (0..3) -> cols ej*4..+3

    for (int s = 0; s < SS; ++s) {
        const int sa = dir ? (SS - 1 - s) : s;
        const u16* hprev = hbuf + ((size_t)((s & 1) * 2 + dir)) * (32 * 512);
        u16*       hnext = hbuf + ((size_t)(((s & 1) ^ 1) * 2 + dir)) * (32 * 512);

        // ---- A: stage xp slice (normal cached loads; overlaps the poll) ----
        if (t < 128) {
            int b = t & 31, gq = t >> 5;
            const u16* xsrc = xp + (size_t)(sa * 32 + b) * GG + gq * 512 + j0;
            bf16x8 v0 = *(const bf16x8*)xsrc;
            bf16x8 v1 = *(const bf16x8*)(xsrc + 8);
            #pragma unroll
            for (int i = 0; i < 8; ++i) {
                xq[b * 65 + gq * 16 + i]     = b2f((u16)v0[i]);
                xq[b * 65 + gq * 16 + 8 + i] = b2f((u16)v1[i]);
            }
        }

        // ---- B: wait for all WGs of this dir to finish step s-1 ----
        if (s > 0 && t < 64) {
            const u32 tgt = (u32)s;
            for (;;) {
                u32 v = tgt;
                if (lane < 32 && lane != wg)
                    v = __hip_atomic_load(myflags + lane * 32, __ATOMIC_RELAXED,
                                          __HIP_MEMORY_SCOPE_AGENT);
                if (__all(v >= tgt)) break;
            }
        }
        __syncthreads();   // (1) poll done + xq visible

        // ---- C: h tile IC -> LDS (swizzled 16B chunks) ----
        {
            int r = t >> 3, seg = t & 7;
            const u64* hp = (const u64*)(hprev + r * 512) + seg * 16;
            u64 v[16];
            #pragma unroll
            for (int i = 0; i < 16; ++i)
                v[i] = __hip_atomic_load(hp + i, __ATOMIC_RELAXED,
                                         __HIP_MEMORY_SCOPE_AGENT);
            u16* lbase = hl + r * 512;
            #pragma unroll
            for (int i2 = 0; i2 < 8; ++i2) {
                int c  = seg * 8 + i2;
                int pc = c ^ (r & 7);
                union { u64 q[2]; bf16x8 v8; } uu;
                uu.q[0] = v[2 * i2]; uu.q[1] = v[2 * i2 + 1];
                *(bf16x8*)(lbase + pc * 8) = uu.v8;
            }
        }
        __syncthreads();   // (2) hl ready

        // ---- D: MFMA, wave g covers gate g, full K=512 ----
        {
            f32x4 acc0 = {0.f, 0.f, 0.f, 0.f}, acc1 = {0.f, 0.f, 0.f, 0.f};
            const int b0 = lane & 15, q = lane >> 4;
            #pragma unroll
            for (int kt = 0; kt < 16; ++kt) {
                int pc = ((kt << 2) + q) ^ (b0 & 7);
                bf16x8 a0 = *(const bf16x8*)&hl[b0 * 512 + pc * 8];
                bf16x8 a1 = *(const bf16x8*)&hl[(b0 + 16) * 512 + pc * 8];
                bf16x8 Bv = *(const bf16x8*)&Wfr[((g * 16 + kt) * 64 + lane) * 8];
                acc0 = __builtin_amdgcn_mfma_f32_16x16x32_bf16(a0, Bv, acc0, 0, 0, 0);
                acc1 = __builtin_amdgcn_mfma_f32_16x16x32_bf16(a1, Bv, acc1, 0, 0, 0);
            }
            // gate plane: col jj = lane&15, row b = mi*16 + (lane>>4)*4 + r
            #pragma unroll
            for (int r = 0; r < 4; ++r) {
                gates[g * 512 + (q * 4 + r) * 16 + b0]      = acc0[r];
                gates[g * 512 + (16 + q * 4 + r) * 16 + b0] = acc1[r];
            }
        }
        __syncthreads();   // (3a) gates ready

        // ---- E: elementwise epilogue (t<128): 4 cols per thread ----
        if (t < 128) {
            float hv[4], cv[4];
            #pragma unroll
            for (int k = 0; k < 4; ++k) {
                int jj = ej * 4 + k;
                float gi = xq[eb * 65 +      jj] + gates[0 * 512 + eb * 16 + jj];
                float gf = xq[eb * 65 + 16 + jj] + gates[1 * 512 + eb * 16 + jj];
                float gg = xq[eb * 65 + 32 + jj] + gates[2 * 512 + eb * 16 + jj];
                float go = xq[eb * 65 + 48 + jj] + gates[3 * 512 + eb * 16 + jj];
                float ig = 1.f / (1.f + __expf(-gi));
                float fg = 1.f / (1.f + __expf(-gf));
                float gt = tanhf(gg);
                float og = 1.f / (1.f + __expf(-go));
                float c  = fg * creg[k] + ig * gt;
                float h  = og * tanhf(c);
                creg[k] = c; cv[k] = c; hv[k] = h;
            }
            union { u64 q; u16 a[4]; } ho;
            #pragma unroll
            for (int k = 0; k < 4; ++k) ho.a[k] = f2b(hv[k]);
            // publish h to IC (bypass L2)
            __hip_atomic_store((u64*)(hnext + eb * 512 + j0 + ej * 4), ho.q,
                               __ATOMIC_RELAXED, __HIP_MEMORY_SCOPE_AGENT);
            if (layer == 0) {
                *(u64*)(hs0 + (size_t)sa * (BB * 1024) + (size_t)eb * 1024
                        + dir * 512 + j0 + ej * 4) = ho.q;
            } else {
                float4 ov = make_float4(hv[0], hv[1], hv[2], hv[3]);
                *(float4*)(out + (size_t)eb * (SS * 1024) + (size_t)sa * 1024
                           + dir * 512 + j0 + ej * 4) = ov;
            }
            if (s == SS - 1) {
                int sl = layer * 2 + dir;
                *(float4*)(fin + (size_t)sl * (32 * 512) + eb * 512 + j0 + ej * 4) =
                    make_float4(hv[0], hv[1], hv[2], hv[3]);
                *(float4*)(fin + 65536 + (size_t)sl * (32 * 512) + eb * 512 + j0 + ej * 4) =
                    make_float4(cv[0], cv[1], cv[2], cv[3]);
            }
        }

        // drain own stores (h is sc1 -> at IC once vmcnt==0), then signal
        asm volatile("s_waitcnt vmcnt(0)" ::: "memory");
        __syncthreads();   // (3) all threads' h stores drained
        if (t == 0)
            __hip_atomic_store(myflags + wg * 32, (u32)(s + 1), __ATOMIC_RELAXED,
                               __HIP_MEMORY_SCOPE_AGENT);
    }
}

// ---------------- workspace layout (bytes) ----------------
#define OFF_XBF   ((size_t)0)                       // 16,777,216
#define OFF_HS0   ((size_t)16777216)                // 33,554,432
#define OFF_XPF   ((size_t)50331648)                // 67,108,864
#define OFF_XPB   ((size_t)117440512)               // 67,108,864
#define OFF_WIH0F ((size_t)184549376)               // 2,097,152
#define OFF_WIH0B ((size_t)186646528)               // 2,097,152
#define OFF_WIH1F ((size_t)188743680)               // 4,194,304
#define OFF_WIH1B ((size_t)192937984)               // 4,194,304
#define OFF_H     ((size_t)197132288)               // 131,072
#define OFF_FLAGS ((size_t)197263360)               // 8,192

extern "C" void kernel_launch(void* const* d_in, const int* in_sizes, int n_in,
                              void* d_out, int out_size, void* d_ws, size_t ws_size,
                              hipStream_t stream) {
    const float* x      = (const float*)d_in[0];
    const float* wih0f  = (const float*)d_in[1];
    const float* whh0f  = (const float*)d_in[2];
    const float* bih0f  = (const float*)d_in[3];
    const float* bhh0f  = (const float*)d_in[4];
    const float* wih0b  = (const float*)d_in[5];
    const float* whh0b  = (const float*)d_in[6];
    const float* bih0b  = (const float*)d_in[7];
    const float* bhh0b  = (const float*)d_in[8];
    const float* wih1f  = (const float*)d_in[9];
    const float* whh1f  = (const float*)d_in[10];
    const float* bih1f  = (const float*)d_in[11];
    const float* bhh1f  = (const float*)d_in[12];
    const float* wih1b  = (const float*)d_in[13];
    const float* whh1b  = (const float*)d_in[14];
    const float* bih1b  = (const float*)d_in[15];
    const float* bhh1b  = (const float*)d_in[16];

    float* out = (float*)d_out;
    char* ws = (char*)d_ws;

    u16* xbf    = (u16*)(ws + OFF_XBF);
    u16* hs0    = (u16*)(ws + OFF_HS0);
    u16* xpf    = (u16*)(ws + OFF_XPF);
    u16* xpb    = (u16*)(ws + OFF_XPB);
    u16* bwih0f = (u16*)(ws + OFF_WIH0F);
    u16* bwih0b = (u16*)(ws + OFF_WIH0B);
    u16* bwih1f = (u16*)(ws + OFF_WIH1F);
    u16* bwih1b = (u16*)(ws + OFF_WIH1B);
    u16* hbuf   = (u16*)(ws + OFF_H);
    u32* flags  = (u32*)(ws + OFF_FLAGS);
    float* fin  = out + 16777216;   // final h stack, then c stack at +65536

    // converts
    k_convert_x<<<1024, 256, 0, stream>>>(x, xbf);
    k_cast<<<512, 256, 0, stream>>>(wih0f, bwih0f, 2048 * 512 / 4);
    k_cast<<<512, 256, 0, stream>>>(wih0b, bwih0b, 2048 * 512 / 4);
    k_cast<<<512, 256, 0, stream>>>(wih1f, bwih1f, 2048 * 1024 / 4);
    k_cast<<<512, 256, 0, stream>>>(wih1b, bwih1b, 2048 * 1024 / 4);

    // layer 0
    hipMemsetAsync(ws + OFF_H, 0, 131072, stream);
    hipMemsetAsync(ws + OFF_FLAGS, 0, 8192, stream);
    k_proj<<<dim3(128, 16, 2), 256, 0, stream>>>(
        xbf, bwih0f, bwih0b, bih0f, bhh0f, bih0b, bhh0b, xpf, xpb, 512);
    k_rec<<<64, 256, 0, stream>>>(xpf, xpb, whh0f, whh0b, hbuf, flags,
                                  hs0, nullptr, fin, 0);

    // layer 1
    hipMemsetAsync(ws + OFF_H, 0, 131072, stream);
    hipMemsetAsync(ws + OFF_FLAGS, 0, 8192, stream);
    k_proj<<<dim3(128, 16, 2), 256, 0, stream>>>(
        hs0, bwih1f, bwih1b, bih1f, bhh1f, bih1b, bhh1b, xpf, xpb, 1024);
    k_rec<<<64, 256, 0, stream>>>(xpf, xpb, whh1f, whh1b, hbuf, flags,
                                  nullptr, out, fin, 1);
}

// Round 5
// 5243.380 us; speedup vs baseline: 4.1519x; 1.1585x over previous
//
#include <hip/hip_runtime.h>

// Problem constants
#define BB 32      // batch
#define SS 512     // seq len
#define II 512     // input size
#define HH 512     // hidden
#define GG 2048    // 4*H

typedef unsigned short u16;
typedef unsigned int   u32;
typedef unsigned long long u64;

typedef __attribute__((ext_vector_type(8))) short bf16x8;
typedef __attribute__((ext_vector_type(4))) float f32x4;

__device__ __forceinline__ float b2f(u16 h) {
    return __uint_as_float(((u32)h) << 16);
}
__device__ __forceinline__ u16 f2b(float f) {  // RNE f32 -> bf16
    u32 u = __float_as_uint(f);
    u32 r = (u + 0x7FFFu + ((u >> 16) & 1u)) >> 16;
    return (u16)r;
}

// ---- global_load_lds helper (16B per lane, uniform LDS base + lane*16) ----
#ifndef __has_builtin
#define __has_builtin(x) 0
#endif
#if __has_builtin(__builtin_amdgcn_global_load_lds)
#define HAVE_GLL 1
#else
#define HAVE_GLL 0
#endif

typedef __attribute__((address_space(1))) void as1_void;
typedef __attribute__((address_space(3))) void as3_void;

__device__ __forceinline__ void gload16(const void* g, void* l, int lane) {
#if HAVE_GLL
    __builtin_amdgcn_global_load_lds((as1_void*)g, (as3_void*)l, 16, 0, 0);
#else
    *(bf16x8*)((char*)l + lane * 16) = *(const bf16x8*)g;
#endif
}

// ---------------- convert x: [B][S][I] f32 -> [S][B][I] bf16 ----------------
__global__ void k_convert_x(const float* __restrict__ x, u16* __restrict__ xbf) {
    const int n4 = BB * SS * II / 4;  // 2,097,152
    for (int e4 = blockIdx.x * blockDim.x + threadIdx.x; e4 < n4;
         e4 += gridDim.x * blockDim.x) {
        int e = e4 * 4;
        int s = e >> 14;         // / (B*I = 16384)
        int b = (e >> 9) & 31;
        int i = e & 511;
        float4 v = *(const float4*)(x + (size_t)b * (SS * II) + (size_t)s * II + i);
        ushort4 o;
        o.x = f2b(v.x); o.y = f2b(v.y); o.z = f2b(v.z); o.w = f2b(v.w);
        *(ushort4*)(xbf + (size_t)s * (BB * II) + (size_t)b * II + i) = o;
    }
}

// ---------------- generic f32 -> bf16 cast ----------------
__global__ void k_cast(const float* __restrict__ src, u16* __restrict__ dst, int n4) {
    for (int e4 = blockIdx.x * blockDim.x + threadIdx.x; e4 < n4;
         e4 += gridDim.x * blockDim.x) {
        float4 v = *(const float4*)(src + (size_t)e4 * 4);
        ushort4 o;
        o.x = f2b(v.x); o.y = f2b(v.y); o.z = f2b(v.z); o.w = f2b(v.w);
        *(ushort4*)(dst + (size_t)e4 * 4) = o;
    }
}

// ---------------- input projection GEMM (128x128 tile, BK=64, MFMA bf16) ----
#define BKP 64

__launch_bounds__(256)
__global__ void k_proj(const u16* __restrict__ A,
                       const u16* __restrict__ Wf_, const u16* __restrict__ Wb_,
                       const float* __restrict__ bihf, const float* __restrict__ bhhf,
                       const float* __restrict__ bihb, const float* __restrict__ bhhb,
                       u16* __restrict__ xpf, u16* __restrict__ xpb,
                       int K) {
    const int dir = blockIdx.z;
    const u16* Wm = dir ? Wb_ : Wf_;
    const float* bih = dir ? bihb : bihf;
    const float* bhh = dir ? bhhb : bhhf;
    u16* xp = dir ? xpb : xpf;

    __shared__ __align__(16) u16 As[128 * BKP];
    __shared__ __align__(16) u16 Bs[128 * BKP];

    const int t    = threadIdx.x;
    const int lane = t & 63;
    const int w    = t >> 6;
    const int wm   = w >> 1, wn = w & 1;
    const int m0   = blockIdx.x * 128;
    const int n0   = blockIdx.y * 128;

    f32x4 acc[4][4] = {};

    for (int kt = 0; kt < K; kt += BKP) {
        #pragma unroll
        for (int i = 0; i < 4; ++i) {
            int c   = (w * 4 + i) * 64 + lane;   // physical chunk 0..1023
            int row = c >> 3;
            int lc  = (c & 7) ^ (row & 7);       // logical chunk within row
            int gk  = kt + lc * 8;
            gload16(A  + (size_t)(m0 + row) * K + gk, (char*)As + (w * 4 + i) * 1024, lane);
            gload16(Wm + (size_t)(n0 + row) * K + gk, (char*)Bs + (w * 4 + i) * 1024, lane);
        }
        __syncthreads();

        #pragma unroll
        for (int ks = 0; ks < 2; ++ks) {
            const int kc = ks * 4 + (lane >> 4);
            bf16x8 af[4], bfr[4];
            #pragma unroll
            for (int mi = 0; mi < 4; ++mi) {
                int row = wm * 64 + mi * 16 + (lane & 15);
                af[mi] = *(const bf16x8*)&As[row * BKP + ((kc ^ (row & 7)) << 3)];
            }
            #pragma unroll
            for (int ni = 0; ni < 4; ++ni) {
                int row = wn * 64 + ni * 16 + (lane & 15);
                bfr[ni] = *(const bf16x8*)&Bs[row * BKP + ((kc ^ (row & 7)) << 3)];
            }
            #pragma unroll
            for (int mi = 0; mi < 4; ++mi)
                #pragma unroll
                for (int ni = 0; ni < 4; ++ni)
                    acc[mi][ni] = __builtin_amdgcn_mfma_f32_16x16x32_bf16(
                        af[mi], bfr[ni], acc[mi][ni], 0, 0, 0);
        }
        __syncthreads();
    }

    #pragma unroll
    for (int ni = 0; ni < 4; ++ni) {
        int n = n0 + wn * 64 + ni * 16 + (lane & 15);
        float bias = bih[n] + bhh[n];
        #pragma unroll
        for (int mi = 0; mi < 4; ++mi) {
            #pragma unroll
            for (int r = 0; r < 4; ++r) {
                int m = m0 + wm * 64 + mi * 16 + (lane >> 4) * 4 + r;
                xp[(size_t)m * GG + n] = f2b(acc[mi][ni][r] + bias);
            }
        }
    }
}

// ---------------- persistent recurrence kernel (stamped-word exchange) -----
// grid = 64 WGs x 256 thr. dir = bid>>5, wg = bid&31 owns 16 h-cols j0..j0+15.
// h exchanged as epoch-stamped u32 words ((bf16<<16)|stamp) via relaxed
// AGENT-scope atomics (IC-coherent). Parity ping-pong makes overwrite safe;
// stamp embeds layer (bit 10) so stale cross-layer/replay data never matches.
// No flags, no fences, no ordering requirements: each word self-validates.
__launch_bounds__(256)
__global__ void k_rec(const u16* __restrict__ xpf, const u16* __restrict__ xpb,
                      const float* __restrict__ whf, const float* __restrict__ whb,
                      u64* __restrict__ Hd,          // [2 par][2 dir][32][256] u64
                      u16* __restrict__ hs0,         // layer0 out [s][b][1024] bf16
                      float* __restrict__ out,       // layer1 out [b][s][1024] f32
                      float* __restrict__ fin,       // final h (65536 f32) then c
                      int layer) {
    const int bid  = blockIdx.x;
    const int dir  = bid >> 5;
    const int wg   = bid & 31;
    const int j0   = wg * 16;
    const u16*  xp = dir ? xpb : xpf;
    const float* W = dir ? whb : whf;

    const int t    = threadIdx.x;
    const int lane = t & 63;
    const int g    = t >> 6;           // wave id = gate

    __shared__ __align__(16) u16 Wfr[64 * 64 * 8];   // frag-order W slice (64 KB)
    __shared__ __align__(16) u16 hl[32 * 512];       // h tile, XOR-swizzled (32 KB)
    __shared__ float xq[32 * 65];                    // xp slice f32
    __shared__ float gates[4 * 32 * 18];             // per-gate planes, stride 18

    // ---- pack W_hh slice into fragment order (once; validated r3) ----
    for (int it = 0; it < 16; ++it) {
        int task = it * 256 + t;           // 0..4095
        int l    = task & 63;
        int blk  = task >> 6;              // 0..63 = gate*16 + ktile
        int gg   = blk >> 4;
        int kt   = blk & 15;
        const float* src = W + (size_t)(gg * 512 + j0 + (l & 15)) * 512
                             + kt * 32 + (l >> 4) * 8;
        float4 v0 = *(const float4*)src;
        float4 v1 = *(const float4*)(src + 4);
        union { bf16x8 v; u16 a[8]; } u;
        u.a[0] = f2b(v0.x); u.a[1] = f2b(v0.y); u.a[2] = f2b(v0.z); u.a[3] = f2b(v0.w);
        u.a[4] = f2b(v1.x); u.a[5] = f2b(v1.y); u.a[6] = f2b(v1.z); u.a[7] = f2b(v1.w);
        *(bf16x8*)&Wfr[task * 8] = u.v;
    }
    __syncthreads();

    // c-state in registers of epilogue threads (t<128): 4 cols each
    float creg[4] = {0.f, 0.f, 0.f, 0.f};
    const int eb = t >> 2;          // epilogue batch row (0..31)
    const int ej = t & 3;           // epilogue col group -> cols j0+ej*4..+3

    // stage-write address constants: thread t covers (row i, k = 2t, 2t+1)
    const int sc_c   = t >> 2;                 // logical 16B chunk within row
    const int sc_sub = (t & 3) * 4;            // byte within chunk

    for (int s = 0; s < SS; ++s) {
        const int sa = dir ? (SS - 1 - s) : s;

        // ---- A: stage xp slice (plain cached loads; overlaps the poll) ----
        if (t < 128) {
            int b = t & 31, gq = t >> 5;
            const u16* xsrc = xp + (size_t)(sa * 32 + b) * GG + gq * 512 + j0;
            bf16x8 v0 = *(const bf16x8*)xsrc;
            bf16x8 v1 = *(const bf16x8*)(xsrc + 8);
            #pragma unroll
            for (int i = 0; i < 8; ++i) {
                xq[b * 65 + gq * 16 + i]     = b2f((u16)v0[i]);
                xq[b * 65 + gq * 16 + 8 + i] = b2f((u16)v1[i]);
            }
        }

        // ---- B: acquire h(s-1): poll stamped words, then stage to LDS ----
        if (s > 0) {
            const u64* Hrd = Hd + ((size_t)((s & 1) * 2 + dir)) * (32 * 256);
            const u32 tgt = (u32)((layer << 10) | s);
            // light spin on row 0 (cheap pre-wait; full verify below)
            for (;;) {
                u64 w = __hip_atomic_load(Hrd + t, __ATOMIC_RELAXED,
                                          __HIP_MEMORY_SCOPE_AGENT);
                bool f = (((u32)w & 0xffffu) == tgt) &&
                         ((((u32)(w >> 32)) & 0xffffu) == tgt);
                if (__all(f)) break;
            }
            // full load + verify-all (retry until every word is fresh)
            u64 v[32];
            for (;;) {
                #pragma unroll
                for (int i = 0; i < 32; ++i)
                    v[i] = __hip_atomic_load(Hrd + i * 256 + t, __ATOMIC_RELAXED,
                                             __HIP_MEMORY_SCOPE_AGENT);
                bool ok = true;
                #pragma unroll
                for (int i = 0; i < 32; ++i) {
                    ok = ok && (((u32)v[i] & 0xffffu) == tgt);
                    ok = ok && ((((u32)(v[i] >> 32)) & 0xffffu) == tgt);
                }
                if (__all(ok)) break;
            }
            // stage: row i, bf16 pair (k=2t, 2t+1) -> 4B LDS write (2-way banks)
            #pragma unroll
            for (int i = 0; i < 32; ++i) {
                u32 two = ((u32)(v[i] >> 16) & 0xffffu) | (((u32)(v[i] >> 48)) << 16);
                int off = i * 1024 + ((sc_c ^ (i & 7)) << 4) + sc_sub;
                *(u32*)((char*)hl + off) = two;
            }
        } else {
            #pragma unroll
            for (int i = 0; i < 32; ++i) {
                int off = i * 1024 + ((sc_c ^ (i & 7)) << 4) + sc_sub;
                *(u32*)((char*)hl + off) = 0u;
            }
        }
        __syncthreads();   // (1) hl + xq ready

        // ---- C: MFMA, wave g covers gate g, full K=512 (validated r3) ----
        {
            f32x4 acc0 = {0.f, 0.f, 0.f, 0.f}, acc1 = {0.f, 0.f, 0.f, 0.f};
            const int b0 = lane & 15, q = lane >> 4;
            #pragma unroll
            for (int kt = 0; kt < 16; ++kt) {
                int pc = ((kt << 2) + q) ^ (b0 & 7);
                bf16x8 a0 = *(const bf16x8*)&hl[b0 * 512 + pc * 8];
                bf16x8 a1 = *(const bf16x8*)&hl[(b0 + 16) * 512 + pc * 8];
                bf16x8 Bv = *(const bf16x8*)&Wfr[((g * 16 + kt) * 64 + lane) * 8];
                acc0 = __builtin_amdgcn_mfma_f32_16x16x32_bf16(a0, Bv, acc0, 0, 0, 0);
                acc1 = __builtin_amdgcn_mfma_f32_16x16x32_bf16(a1, Bv, acc1, 0, 0, 0);
            }
            // plane [g][batch][jj], batch-stride 18: row = q*4+r (+16), col = jj
            #pragma unroll
            for (int r = 0; r < 4; ++r) {
                gates[g * 576 + (q * 4 + r) * 18 + b0]      = acc0[r];
                gates[g * 576 + (16 + q * 4 + r) * 18 + b0] = acc1[r];
            }
        }
        __syncthreads();   // (2) gates ready

        // ---- D: elementwise epilogue (t<128): (eb, cols j0+ej*4..+3) ----
        if (t < 128) {
            float hv4[4], cv4[4];
            #pragma unroll
            for (int k = 0; k < 4; ++k) {
                int jj = ej * 4 + k;
                float gi = xq[eb * 65 +      jj] + gates[0 * 576 + eb * 18 + jj];
                float gf = xq[eb * 65 + 16 + jj] + gates[1 * 576 + eb * 18 + jj];
                float gg = xq[eb * 65 + 32 + jj] + gates[2 * 576 + eb * 18 + jj];
                float go = xq[eb * 65 + 48 + jj] + gates[3 * 576 + eb * 18 + jj];
                float ig = 1.f / (1.f + __expf(-gi));
                float fg = 1.f / (1.f + __expf(-gf));
                float gt = tanhf(gg);
                float og = 1.f / (1.f + __expf(-go));
                float c  = fg * creg[k] + ig * gt;
                float h  = og * tanhf(c);
                creg[k] = c; cv4[k] = c; hv4[k] = h;
            }
            // publish stamped h words (parity ping-pong)
            u64* Hwr = Hd + ((size_t)(((s + 1) & 1) * 2 + dir)) * (32 * 256);
            const u32 pst = (u32)((layer << 10) | (s + 1));
            u32 w0 = ((u32)f2b(hv4[0]) << 16) | pst;
            u32 w1 = ((u32)f2b(hv4[1]) << 16) | pst;
            u32 w2 = ((u32)f2b(hv4[2]) << 16) | pst;
            u32 w3 = ((u32)f2b(hv4[3]) << 16) | pst;
            u64* dst = Hwr + eb * 256 + ((j0 + ej * 4) >> 1);
            __hip_atomic_store(dst,     (u64)w0 | ((u64)w1 << 32),
                               __ATOMIC_RELAXED, __HIP_MEMORY_SCOPE_AGENT);
            __hip_atomic_store(dst + 1, (u64)w2 | ((u64)w3 << 32),
                               __ATOMIC_RELAXED, __HIP_MEMORY_SCOPE_AGENT);

            union { u64 q; u16 a[4]; } ho;
            #pragma unroll
            for (int k = 0; k < 4; ++k) ho.a[k] = f2b(hv4[k]);
            if (layer == 0) {
                *(u64*)(hs0 + (size_t)sa * (BB * 1024) + (size_t)eb * 1024
                        + dir * 512 + j0 + ej * 4) = ho.q;
            } else {
                *(float4*)(out + (size_t)eb * (SS * 1024) + (size_t)sa * 1024
                           + dir * 512 + j0 + ej * 4) =
                    make_float4(hv4[0], hv4[1], hv4[2], hv4[3]);
            }
            if (s == SS - 1) {
                int sl = layer * 2 + dir;
                *(float4*)(fin + (size_t)sl * (32 * 512) + eb * 512 + j0 + ej * 4) =
                    make_float4(hv4[0], hv4[1], hv4[2], hv4[3]);
                *(float4*)(fin + 65536 + (size_t)sl * (32 * 512) + eb * 512 + j0 + ej * 4) =
                    make_float4(cv4[0], cv4[1], cv4[2], cv4[3]);
            }
        }
        __syncthreads();   // (3) xq/gates free for next step
    }
}

// ---------------- workspace layout (bytes) ----------------
#define OFF_XBF   ((size_t)0)                       // 16,777,216
#define OFF_HS0   ((size_t)16777216)                // 33,554,432
#define OFF_XPF   ((size_t)50331648)                // 67,108,864
#define OFF_XPB   ((size_t)117440512)               // 67,108,864
#define OFF_WIH0F ((size_t)184549376)               // 2,097,152
#define OFF_WIH0B ((size_t)186646528)               // 2,097,152
#define OFF_WIH1F ((size_t)188743680)               // 4,194,304
#define OFF_WIH1B ((size_t)192937984)               // 4,194,304
#define OFF_HST   ((size_t)197132288)               // 262,144 (stamped h)

extern "C" void kernel_launch(void* const* d_in, const int* in_sizes, int n_in,
                              void* d_out, int out_size, void* d_ws, size_t ws_size,
                              hipStream_t stream) {
    const float* x      = (const float*)d_in[0];
    const float* wih0f  = (const float*)d_in[1];
    const float* whh0f  = (const float*)d_in[2];
    const float* bih0f  = (const float*)d_in[3];
    const float* bhh0f  = (const float*)d_in[4];
    const float* wih0b  = (const float*)d_in[5];
    const float* whh0b  = (const float*)d_in[6];
    const float* bih0b  = (const float*)d_in[7];
    const float* bhh0b  = (const float*)d_in[8];
    const float* wih1f  = (const float*)d_in[9];
    const float* whh1f  = (const float*)d_in[10];
    const float* bih1f  = (const float*)d_in[11];
    const float* bhh1f  = (const float*)d_in[12];
    const float* wih1b  = (const float*)d_in[13];
    const float* whh1b  = (const float*)d_in[14];
    const float* bih1b  = (const float*)d_in[15];
    const float* bhh1b  = (const float*)d_in[16];

    float* out = (float*)d_out;
    char* ws = (char*)d_ws;

    u16* xbf    = (u16*)(ws + OFF_XBF);
    u16* hs0    = (u16*)(ws + OFF_HS0);
    u16* xpf    = (u16*)(ws + OFF_XPF);
    u16* xpb    = (u16*)(ws + OFF_XPB);
    u16* bwih0f = (u16*)(ws + OFF_WIH0F);
    u16* bwih0b = (u16*)(ws + OFF_WIH0B);
    u16* bwih1f = (u16*)(ws + OFF_WIH1F);
    u16* bwih1b = (u16*)(ws + OFF_WIH1B);
    u64* Hd     = (u64*)(ws + OFF_HST);
    float* fin  = out + 16777216;   // final h stack, then c stack at +65536

    // converts
    k_convert_x<<<1024, 256, 0, stream>>>(x, xbf);
    k_cast<<<512, 256, 0, stream>>>(wih0f, bwih0f, 2048 * 512 / 4);
    k_cast<<<512, 256, 0, stream>>>(wih0b, bwih0b, 2048 * 512 / 4);
    k_cast<<<512, 256, 0, stream>>>(wih1f, bwih1f, 2048 * 1024 / 4);
    k_cast<<<512, 256, 0, stream>>>(wih1b, bwih1b, 2048 * 1024 / 4);

    // zero stamped-h buffer once (first-call garbage; stale stamps are
    // layer-tagged so no inter-layer or inter-replay reset is needed)
    hipMemsetAsync(ws + OFF_HST, 0, 262144, stream);

    // layer 0
    k_proj<<<dim3(128, 16, 2), 256, 0, stream>>>(
        xbf, bwih0f, bwih0b, bih0f, bhh0f, bih0b, bhh0b, xpf, xpb, 512);
    k_rec<<<64, 256, 0, stream>>>(xpf, xpb, whh0f, whh0b, Hd,
                                  hs0, nullptr, fin, 0);

    // layer 1
    k_proj<<<dim3(128, 16, 2), 256, 0, stream>>>(
        hs0, bwih1f, bwih1b, bih1f, bhh1f, bih1b, bhh1b, xpf, xpb, 1024);
    k_rec<<<64, 256, 0, stream>>>(xpf, xpb, whh1f, whh1b, Hd,
                                  nullptr, out, fin, 1);
}